// Round 15
// baseline (298.379 us; speedup 1.0000x reference)
//
#include <hip/hip_runtime.h>
#include <stdint.h>

typedef uint16_t u16;
typedef short s16x8 __attribute__((ext_vector_type(8)));
typedef float f32x4 __attribute__((ext_vector_type(4)));
typedef unsigned short u16x4 __attribute__((ext_vector_type(4)));
typedef uint32_t u32;
typedef u32 u32x2 __attribute__((ext_vector_type(2)));
typedef u32 u32x4 __attribute__((ext_vector_type(4)));

#define MFMA16(a,b,c) __builtin_amdgcn_mfma_f32_16x16x32_bf16((a),(b),(c),0,0,0)
#define QSCALE 0.18033688011112042f   // 0.125 * log2(e)

__device__ __forceinline__ float b2f(u16 b){
  union { u32 u; float f; } v; v.u = ((u32)b)<<16; return v.f;
}
__device__ __forceinline__ u16 f2b(float f){
  union { float f; u32 u; } v; v.f = f;
  return (u16)((v.u + 0x7fffu + ((v.u>>16)&1u))>>16);
}
__device__ __forceinline__ u32 fbits(float f){
  union { float f; u32 u; } v; v.f = f; return v.u;
}
__device__ __forceinline__ void load_lds_16B(const void* g, void* l){
  __builtin_amdgcn_global_load_lds((const __attribute__((address_space(1))) void*)g,
                                   (__attribute__((address_space(3))) void*)l, 16, 0, 0);
}

// ---------------- kernel 1: pure fp32->bf16 conversion (R12-identical) -------
__global__ __launch_bounds__(256) void conv_kernel(
    const float* __restrict__ x, u16* __restrict__ xb,
    const float* __restrict__ W0, const float* __restrict__ W1,
    const float* __restrict__ W2, const float* __restrict__ W3,
    u16* __restrict__ Wb,
    const float* __restrict__ A0, const float* __restrict__ A1,
    const float* __restrict__ A2, const float* __restrict__ A3,
    u16* __restrict__ Abf)
{
  const int bid = blockIdx.x;
  if (bid < 1024){
    const int g = bid*256 + threadIdx.x;
#pragma unroll
    for (int t=0;t<4;t++){
      const int i4 = g + t*262144;
      const f32x4 v = *(const f32x4*)(x + (size_t)i4*4);
      u16x4 o;
#pragma unroll
      for (int j=0;j<4;j++) o[j] = f2b(v[j]);
      *(u16x4*)(xb + (size_t)i4*4) = o;
    }
    return;
  }
  if (bid < 2048){
    const int cv = bid - 1024;
    const int y = cv>>8;
    const float* src = (y==0)?W0:(y==1)?W1:(y==2)?W2:W3;
    u16* dst = Wb + (size_t)y*1048576;
    const int g = (cv&255)*256 + threadIdx.x;
#pragma unroll
    for (int t=0;t<4;t++){
      const int i4 = g + t*65536;
      const f32x4 v = *(const f32x4*)(src + (size_t)i4*4);
      u16x4 o;
#pragma unroll
      for (int j=0;j<4;j++) o[j] = f2b(v[j]);
      *(u16x4*)(dst + (size_t)i4*4) = o;
    }
    return;
  }
  // A conversion: 4 mats x 16 rows x 128 chunks of 8 u16
  for (int w = threadIdx.x; w < 8192; w += 256){
    const int proj = w >> 11, rem = w & 2047;
    const int row = rem >> 7, c8 = (rem & 127) << 3;
    u16x4 o0 = u16x4{0,0,0,0}, o1 = u16x4{0,0,0,0};
    if (row < 8){
      const float* ap = ((proj==0)?A0:(proj==1)?A1:(proj==2)?A2:A3) + row*1024 + c8;
      const f32x4 v0 = *(const f32x4*)(ap);
      const f32x4 v1 = *(const f32x4*)(ap+4);
#pragma unroll
      for (int j=0;j<4;j++){ o0[j] = f2b(v0[j]); o1[j] = f2b(v1[j]); }
    }
    u16* dp = Abf + (size_t)(proj*16 + row)*1024 + c8;
    *(u16x4*)(dp)   = o0;
    *(u16x4*)(dp+4) = o1;
  }
}

// ---------------- fused QKV GEMM (R12-identical) -----------------------------
__global__ __launch_bounds__(256,2) void gemm_qkv_kernel(
    const u16* __restrict__ Xb, const u16* __restrict__ Wb,
    const float* __restrict__ bq, const float* __restrict__ bk, const float* __restrict__ bv,
    const u16* __restrict__ Abf,
    const float* __restrict__ Blq, const float* __restrict__ Blk, const float* __restrict__ Blv,
    u16* __restrict__ Qb, u16* __restrict__ Kb, u16* __restrict__ Vtb)
{
  __shared__ u16 sm[16896];                 // staging (16384) U V-transpose / tT
  u16* AtB = sm;                            // [2][128*32]
  u16* BtB = sm + 8192;                     // [2][128*32]
  const int tid = threadIdx.x;
  const int wid = tid>>6, lane = tid&63;
  const int quad = lane>>4, l16 = lane&15;
  const int wm = wid>>1, wn = wid&1;
  const int proj = blockIdx.x>>3;
  const int n0 = (blockIdx.x&7)<<7, m0 = blockIdx.y<<7;
  const u16* W = Wb + (size_t)proj*1048576;
  const u16* AbP = Abf + (size_t)proj*16384;
  const float* bias = (proj==0)?bq:(proj==1)?bk:bv;
  const float* Bl   = (proj==0)?Blq:(proj==1)?Blk:Blv;
  const float scale = (proj==0)?QSCALE:1.0f;

  f32x4 acc[4][4];
  f32x4 acc_t[4];
#pragma unroll
  for (int i=0;i<4;i++){
#pragma unroll
    for (int j=0;j<4;j++) acc[i][j] = f32x4{0.f,0.f,0.f,0.f};
    acc_t[i] = f32x4{0.f,0.f,0.f,0.f};
  }

  for (int k0=0;k0<1024;k0+=64){
#pragma unroll
    for (int half=0; half<2; half++){
#pragma unroll
      for (int p=0;p<2;p++){
        const int s = wid*128 + p*64 + lane;
        const int row = s>>2, c = s&3;
        load_lds_16B(Xb + (size_t)(m0+row)*1024 + k0 + half*32 + c*8, AtB + half*4096 + (wid*128+p*64)*8);
        load_lds_16B(W  + (size_t)(n0+row)*1024 + k0 + half*32 + c*8, BtB + half*4096 + (wid*128+p*64)*8);
      }
    }
    __syncthreads();
#pragma unroll
    for (int half=0; half<2; half++){
      s16x8 af[4], bfr[4];
#pragma unroll
      for (int t=0;t<4;t++){
        const int r = wm*64 + t*16 + l16;
        af[t]  = *(const s16x8*)(AtB + half*4096 + r*32 + quad*8);
        const int c = wn*64 + t*16 + l16;
        bfr[t] = *(const s16x8*)(BtB + half*4096 + c*32 + quad*8);
      }
      const s16x8 abf = *(const s16x8*)(AbP + (size_t)l16*1024 + k0 + half*32 + quad*8);
#pragma unroll
      for (int tm=0;tm<4;tm++){
#pragma unroll
        for (int tn=0;tn<4;tn++)
          acc[tm][tn] = MFMA16(af[tm], bfr[tn], acc[tm][tn]);
        acc_t[tm] = MFMA16(af[tm], abf, acc_t[tm]);
      }
    }
    __syncthreads();
  }

  // transpose acc_t (C-layout: m=quad*4+rg, r=l16) -> tT[m][r] in LDS
  float* tT = (float*)sm;
  if (wn==0 && l16<8){
#pragma unroll
    for (int tm=0;tm<4;tm++)
#pragma unroll
      for (int rg=0;rg<4;rg++)
        tT[(wm*64 + tm*16 + quad*4 + rg)*8 + l16] = acc_t[tm][rg];
  }
  __syncthreads();

  // LoRA term via one K=8 (zero-padded to 32) MFMA per acc tile: quad0 holds k=0..7
  s16x8 tf[4], bfl[4];
#pragma unroll
  for (int t=0;t<4;t++){ tf[t] = s16x8{0,0,0,0,0,0,0,0}; bfl[t] = s16x8{0,0,0,0,0,0,0,0}; }
  if (quad==0){
#pragma unroll
    for (int tm=0;tm<4;tm++){
      const float* tp = tT + (wm*64 + tm*16 + l16)*8;
#pragma unroll
      for (int j=0;j<8;j++) tf[tm][j] = (short)f2b(2.0f*tp[j]);
    }
#pragma unroll
    for (int tn=0;tn<4;tn++){
      const float* bp = Bl + (size_t)(n0 + wn*64 + tn*16 + l16)*8;
      const f32x4 b0 = *(const f32x4*)(bp);
      const f32x4 b1 = *(const f32x4*)(bp+4);
#pragma unroll
      for (int j=0;j<4;j++){ bfl[tn][j] = (short)f2b(b0[j]); bfl[tn][4+j] = (short)f2b(b1[j]); }
    }
  }
#pragma unroll
  for (int tm=0;tm<4;tm++)
#pragma unroll
    for (int tn=0;tn<4;tn++)
      acc[tm][tn] = MFMA16(tf[tm], bfl[tn], acc[tm][tn]);

  if (proj==2){
    // V: bf16 -> LDS [n_local][m_local] pitch 132 -> coalesced Vt stores
    __syncthreads();   // tT reads done everywhere before sm reuse
#pragma unroll
    for (int tn=0;tn<4;tn++){
      const int nl = wn*64 + tn*16 + l16;
      const float bn = bias[n0+nl];
#pragma unroll
      for (int tm=0;tm<4;tm++){
        const int ml = wm*64 + tm*16 + quad*4;
        u16x4 pk;
#pragma unroll
        for (int rg=0;rg<4;rg++) pk[rg] = f2b(acc[tm][tn][rg]+bn);
        *(u16x4*)(sm + nl*132 + ml) = pk;
      }
    }
    __syncthreads();
    const int batch = m0>>11, sbase = m0&2047;
#pragma unroll
    for (int p=0;p<8;p++){
      const int idx = p*256 + tid;
      const int row = idx>>4, c16 = idx&15;
      const s16x8 v = *(const s16x8*)(sm + row*132 + c16*8);
      const int ng = n0 + row, hh = ng>>6, dd = ng&63;
      *(s16x8*)(Vtb + (size_t)((batch*16+hh)*64+dd)*2048 + sbase + c16*8) = v;
    }
  } else {
#pragma unroll
    for (int tn=0;tn<4;tn++){
      const int n = n0 + wn*64 + tn*16 + l16;
      const float bn = bias[n];
#pragma unroll
      for (int tm=0;tm<4;tm++){
        const int mb = m0 + wm*64 + tm*16 + quad*4;
        if (proj==0){
#pragma unroll
          for (int rg=0;rg<4;rg++) Qb[(size_t)(mb+rg)*1024 + n] = f2b((acc[tm][tn][rg]+bn)*scale);
        } else {
#pragma unroll
          for (int rg=0;rg<4;rg++) Kb[(size_t)(mb+rg)*1024 + n] = f2b(acc[tm][tn][rg]+bn);
        }
      }
    }
  }
}

// ---------------- O-proj GEMM (R12-identical) --------------------------------
__global__ __launch_bounds__(256,2) void gemm_o_kernel(
    const u16* __restrict__ Xb, const u16* __restrict__ W,
    const float* __restrict__ bias, const u16* __restrict__ Abf,
    const float* __restrict__ Bl, float* __restrict__ Out)
{
  __shared__ u16 At[2][128*32];
  __shared__ u16 Bt[2][64*32];
  const int tid = threadIdx.x;
  const int wid = tid>>6, lane = tid&63;
  const int quad = lane>>4, l16 = lane&15;
  const int wm = wid>>1, wn = wid&1;
  const int m0 = blockIdx.y<<7, n0 = blockIdx.x<<6;
  const u16* AbP = Abf + (size_t)3*16384;

  f32x4 acc[4][2];
  f32x4 acc_t[4];
#pragma unroll
  for (int i=0;i<4;i++){
#pragma unroll
    for (int j=0;j<2;j++) acc[i][j] = f32x4{0.f,0.f,0.f,0.f};
    acc_t[i] = f32x4{0.f,0.f,0.f,0.f};
  }

  for (int k0=0;k0<1024;k0+=64){
#pragma unroll
    for (int half=0; half<2; half++){
#pragma unroll
      for (int p=0;p<2;p++){
        const int s = wid*128 + p*64 + lane;
        const int row = s>>2, c = s&3;
        load_lds_16B(Xb + (size_t)(m0+row)*1024 + k0 + half*32 + c*8, At[half] + (wid*128+p*64)*8);
      }
      { const int s = wid*64 + lane;
        const int row = s>>2, c = s&3;
        load_lds_16B(W + (size_t)(n0+row)*1024 + k0 + half*32 + c*8, Bt[half] + (wid*64)*8); }
    }
    __syncthreads();
#pragma unroll
    for (int half=0; half<2; half++){
      s16x8 af[4], bfr[2];
#pragma unroll
      for (int t=0;t<4;t++){
        const int r = wm*64 + t*16 + l16;
        af[t] = *(const s16x8*)(At[half] + r*32 + quad*8);
      }
#pragma unroll
      for (int t=0;t<2;t++){
        const int c = wn*32 + t*16 + l16;
        bfr[t] = *(const s16x8*)(Bt[half] + c*32 + quad*8);
      }
      const s16x8 abf = *(const s16x8*)(AbP + (size_t)l16*1024 + k0 + half*32 + quad*8);
#pragma unroll
      for (int tm=0;tm<4;tm++){
#pragma unroll
        for (int tn=0;tn<2;tn++)
          acc[tm][tn] = MFMA16(af[tm], bfr[tn], acc[tm][tn]);
        acc_t[tm] = MFMA16(af[tm], abf, acc_t[tm]);
      }
    }
    __syncthreads();
  }

  float* tT = (float*)At;
  if (wn==0 && l16<8){
#pragma unroll
    for (int tm=0;tm<4;tm++)
#pragma unroll
      for (int rg=0;rg<4;rg++)
        tT[(wm*64 + tm*16 + quad*4 + rg)*8 + l16] = acc_t[tm][rg];
  }
  __syncthreads();

  s16x8 tf[4], bfl[2];
#pragma unroll
  for (int t=0;t<4;t++) tf[t] = s16x8{0,0,0,0,0,0,0,0};
#pragma unroll
  for (int t=0;t<2;t++) bfl[t] = s16x8{0,0,0,0,0,0,0,0};
  if (quad==0){
#pragma unroll
    for (int tm=0;tm<4;tm++){
      const float* tp = tT + (wm*64 + tm*16 + l16)*8;
#pragma unroll
      for (int j=0;j<8;j++) tf[tm][j] = (short)f2b(2.0f*tp[j]);
    }
#pragma unroll
    for (int tn=0;tn<2;tn++){
      const float* bp = Bl + (size_t)(n0 + wn*32 + tn*16 + l16)*8;
      const f32x4 b0 = *(const f32x4*)(bp);
      const f32x4 b1 = *(const f32x4*)(bp+4);
#pragma unroll
      for (int j=0;j<4;j++){ bfl[tn][j] = (short)f2b(b0[j]); bfl[tn][4+j] = (short)f2b(b1[j]); }
    }
  }
#pragma unroll
  for (int tm=0;tm<4;tm++)
#pragma unroll
    for (int tn=0;tn<2;tn++)
      acc[tm][tn] = MFMA16(tf[tm], bfl[tn], acc[tm][tn]);

#pragma unroll
  for (int tn=0;tn<2;tn++){
    const int n = n0 + wn*32 + tn*16 + l16;
    const float bn = bias[n];
#pragma unroll
    for (int tm=0;tm<4;tm++){
      const int mb = m0 + wm*64 + tm*16 + quad*4;
#pragma unroll
      for (int rg=0;rg<4;rg++)
        Out[(size_t)(mb+rg)*1024 + n] = acc[tm][tn][rg] + bn;
    }
  }
}

// ---------------- MFMA flash attention v9: NO K/V LDS staging ----------------
// R12 counters: HBM 5.4%, FETCH 12.3MB -> K/V panels are L2-resident (XCD
// swizzle co-locates all 16 q-blocks of a panel). Per common-mistake #7
// (m169: dropping LDS staging of L2-fit attn data was +26%), read K/V
// fragments DIRECTLY from global: deletes 32 barriers/block, the kreg/vreg
// machinery, and 4.26M LDS conflict cycles. All 8 waves run the 2048-key loop
// fully independently (16 waves/CU self-paced hide ~200cy L2 latency).
// Per-fragment access = 16 rows x one fully-used 64B line. LDS = 35KB
// epilogue merge only. Data path & numerics bit-identical to v8.
__global__ __launch_bounds__(512,4) void attn_kernel(
    const u16* __restrict__ Q, const u16* __restrict__ K,
    const u16* __restrict__ Vt, u16* __restrict__ Out)
{
  __shared__ float ep[128*68];
  __shared__ float lw[128];
  const int tid = threadIdx.x;
  const int wid = tid>>6, lane = tid&63;
  const int quad = lane>>4, l16 = lane&15;
  const int lin = blockIdx.x + (blockIdx.y<<4) + (blockIdx.z<<8);
  const int swz = (lin&7)*64 + (lin>>3);
  const int q0 = (swz&15)<<7;
  const int h  = (swz>>4)&15;
  const int nb = swz>>8;
  const int qg = wid>>1;
  const int kh = wid&1;
  const int qw = qg*32;

  s16x8 qf[2][2];
#pragma unroll
  for (int g=0;g<2;g++){
    const int row = q0 + qw + g*16 + l16;
#pragma unroll
    for (int dh=0;dh<2;dh++)
      qf[g][dh] = *(const s16x8*)(Q + (size_t)(nb*2048+row)*1024 + h*64 + dh*32 + quad*8);
  }
  f32x4 OT[2][4];
  f32x4 Lacc[2];
#pragma unroll
  for (int g=0;g<2;g++){
#pragma unroll
    for (int td=0;td<4;td++) OT[g][td] = f32x4{0.f,0.f,0.f,0.f};
    Lacc[g] = f32x4{0.f,0.f,0.f,0.f};
  }
  s16x8 ones;
#pragma unroll
  for (int j=0;j<8;j++) ones[j] = (short)0x3F80;

  const u16* Kbase  = K  + (size_t)(nb*2048)*1024 + h*64;
  const u16* Vtbase = Vt + (size_t)((nb*16+h)*64)*2048;

  for (int t=0;t<16;t++){
    const int kt = t*128;
#pragma unroll
    for (int kb=0;kb<2;kb++){
      const int kcol = kt + kh*64 + kb*32;     // this wave's 32-key chunk base
      u32 ew[2][2], ow[2][2];
#pragma unroll
      for (int sel=0;sel<2;sel++){
        const int key = kcol + sel*16 + l16;
        const u16* kp = Kbase + (size_t)key*1024 + quad*8;
        const s16x8 kf0 = *(const s16x8*)(kp);
        const s16x8 kf1 = *(const s16x8*)(kp + 32);
#pragma unroll
        for (int g=0;g<2;g++){
          f32x4 z = f32x4{0.f,0.f,0.f,0.f};
          z = MFMA16(kf0, qf[g][0], z);
          z = MFMA16(kf1, qf[g][1], z);
          const float p0 = __builtin_amdgcn_exp2f(z[0]);
          const float p1 = __builtin_amdgcn_exp2f(z[1]);
          const float p2 = __builtin_amdgcn_exp2f(z[2]);
          const float p3 = __builtin_amdgcn_exp2f(z[3]);
          const u32 w0 = __builtin_amdgcn_perm(fbits(p1), fbits(p0), 0x07060302u);
          const u32 w1 = __builtin_amdgcn_perm(fbits(p3), fbits(p2), 0x07060302u);
          if (sel==0){ ew[g][0]=w0; ew[g][1]=w1; } else { ow[g][0]=w0; ow[g][1]=w1; }
        }
      }
      s16x8 pf[2];
#pragma unroll
      for (int g=0;g<2;g++){
        const u32x2 r32 = __builtin_amdgcn_permlane32_swap(ew[g][0], ow[g][0], false, false);
        const u32x2 r16 = __builtin_amdgcn_permlane16_swap(r32[0], r32[1], false, false);
        const u32x2 s32 = __builtin_amdgcn_permlane32_swap(ew[g][1], ow[g][1], false, false);
        const u32x2 s16v = __builtin_amdgcn_permlane16_swap(s32[0], s32[1], false, false);
        u32x4 pw; pw[0]=r16[0]; pw[1]=s16v[0]; pw[2]=r16[1]; pw[3]=s16v[1];
        pf[g] = __builtin_bit_cast(s16x8, pw);
      }
      __builtin_amdgcn_s_setprio(1);
#pragma unroll
      for (int td=0;td<4;td++){
        const s16x8 vf = *(const s16x8*)(Vtbase + (size_t)(td*16+l16)*2048 + kcol + quad*8);
#pragma unroll
        for (int g=0;g<2;g++)
          OT[g][td] = MFMA16(vf, pf[g], OT[g][td]);
      }
#pragma unroll
      for (int g=0;g<2;g++)
        Lacc[g] = MFMA16(ones, pf[g], Lacc[g]);
      __builtin_amdgcn_s_setprio(0);
    }
  }

  // epilogue: merge the two key-halves via LDS, then scale + RNE pack
  if (kh==1){
#pragma unroll
    for (int g=0;g<2;g++){
      const int q = qw + g*16 + l16;
#pragma unroll
      for (int td=0;td<4;td++)
        *(f32x4*)(ep + q*68 + td*16 + quad*4) = OT[g][td];
      if (quad==0) lw[q] = Lacc[g][0];
    }
  }
  __syncthreads();
  if (kh==0){
#pragma unroll
    for (int g=0;g<2;g++){
      const int q = qw + g*16 + l16;
      const float linv = 1.0f / (Lacc[g][0] + lw[q]);
      const int qout = q0 + q;
#pragma unroll
      for (int td=0;td<4;td++){
        const f32x4 o2 = *(const f32x4*)(ep + q*68 + td*16 + quad*4);
        u16x4 pk;
#pragma unroll
        for (int rg=0;rg<4;rg++) pk[rg] = f2b((OT[g][td][rg]+o2[rg])*linv);
        *(u16x4*)(Out + (size_t)(nb*2048+qout)*1024 + h*64 + td*16 + quad*4) = pk;
      }
    }
  }
}

extern "C" void kernel_launch(void* const* d_in, const int* in_sizes, int n_in,
                              void* d_out, int out_size, void* d_ws, size_t ws_size,
                              hipStream_t stream)
{
  const float* x  = (const float*)d_in[0];
  const float* Wq = (const float*)d_in[1];  const float* bq = (const float*)d_in[2];
  const float* Aq = (const float*)d_in[3];  const float* Bq = (const float*)d_in[4];
  const float* Wk = (const float*)d_in[5];  const float* bk = (const float*)d_in[6];
  const float* Ak = (const float*)d_in[7];  const float* Bk = (const float*)d_in[8];
  const float* Wv = (const float*)d_in[9];  const float* bv = (const float*)d_in[10];
  const float* Av = (const float*)d_in[11]; const float* Bv = (const float*)d_in[12];
  const float* Wo = (const float*)d_in[13]; const float* bo = (const float*)d_in[14];
  const float* Ao = (const float*)d_in[15]; const float* Bo = (const float*)d_in[16];

  char* ws = (char*)d_ws;
  u16* Abf = (u16*)(ws + 0);                   // 4x16x1024 bf16 = 128 KB
  u16* xb  = (u16*)(ws + 524288);              // 8 MB; Ab aliases (xb dead after QKV)
  u16* Ab  = xb;
  u16* Wb  = (u16*)(ws + 524288 + 8388608);
  u16* Qb  = (u16*)(ws + 524288 + 2*8388608);
  u16* Kb  = (u16*)(ws + 524288 + 3*8388608);
  u16* Vtb = (u16*)(ws + 524288 + 4*8388608);

  conv_kernel<<<dim3(2049),256,0,stream>>>(x, xb, Wq, Wk, Wv, Wo, Wb,
                                           Aq, Ak, Av, Ao, Abf);
  gemm_qkv_kernel<<<dim3(24,32),256,0,stream>>>(xb, Wb, bq, bk, bv, Abf,
                                                Bq, Bk, Bv, Qb, Kb, Vtb);
  attn_kernel<<<dim3(16,16,2),512,0,stream>>>(Qb, Kb, Vtb, Ab);
  gemm_o_kernel<<<dim3(16,32),256,0,stream>>>(Ab, Wb + (size_t)3*1048576, bo, Abf, Bo,
                                              (float*)d_out);
}

// Round 16
// 223.822 us; speedup vs baseline: 1.3331x; 1.3331x over previous
//
#include <hip/hip_runtime.h>
#include <stdint.h>

typedef uint16_t u16;
typedef short s16x8 __attribute__((ext_vector_type(8)));
typedef float f32x4 __attribute__((ext_vector_type(4)));
typedef unsigned short u16x4 __attribute__((ext_vector_type(4)));
typedef uint32_t u32;
typedef u32 u32x2 __attribute__((ext_vector_type(2)));
typedef u32 u32x4 __attribute__((ext_vector_type(4)));

#define MFMA16(a,b,c) __builtin_amdgcn_mfma_f32_16x16x32_bf16((a),(b),(c),0,0,0)
#define QSCALE 0.18033688011112042f   // 0.125 * log2(e)

__device__ __forceinline__ float b2f(u16 b){
  union { u32 u; float f; } v; v.u = ((u32)b)<<16; return v.f;
}
__device__ __forceinline__ u16 f2b(float f){
  union { float f; u32 u; } v; v.f = f;
  return (u16)((v.u + 0x7fffu + ((v.u>>16)&1u))>>16);
}
__device__ __forceinline__ u32 fbits(float f){
  union { float f; u32 u; } v; v.f = f; return v.u;
}
__device__ __forceinline__ void load_lds_16B(const void* g, void* l){
  __builtin_amdgcn_global_load_lds((const __attribute__((address_space(1))) void*)g,
                                   (__attribute__((address_space(3))) void*)l, 16, 0, 0);
}

// ---------------- kernel 1: pure fp32->bf16 conversion -----------------------
// grid 2049: [0,1024) x->xb; [1024,2048) W0..W3->Wb; block 2048: A matrices ->
// Abf[4][16][1024] bf16 (rows 8..15 zero-padded for the MFMA B-operand).
// NOTE (R11 lesson): keeping the bf16 Wb round-trip is deliberate — fp32-W
// reg-staging inside the GEMMs put a synchronous load->convert->ds_write
// chain on the K-loop critical path and cost +21us. Parallel bandwidth is
// cheaper than serial latency here.
__global__ __launch_bounds__(256) void conv_kernel(
    const float* __restrict__ x, u16* __restrict__ xb,
    const float* __restrict__ W0, const float* __restrict__ W1,
    const float* __restrict__ W2, const float* __restrict__ W3,
    u16* __restrict__ Wb,
    const float* __restrict__ A0, const float* __restrict__ A1,
    const float* __restrict__ A2, const float* __restrict__ A3,
    u16* __restrict__ Abf)
{
  const int bid = blockIdx.x;
  if (bid < 1024){
    const int g = bid*256 + threadIdx.x;
#pragma unroll
    for (int t=0;t<4;t++){
      const int i4 = g + t*262144;
      const f32x4 v = *(const f32x4*)(x + (size_t)i4*4);
      u16x4 o;
#pragma unroll
      for (int j=0;j<4;j++) o[j] = f2b(v[j]);
      *(u16x4*)(xb + (size_t)i4*4) = o;
    }
    return;
  }
  if (bid < 2048){
    const int cv = bid - 1024;
    const int y = cv>>8;
    const float* src = (y==0)?W0:(y==1)?W1:(y==2)?W2:W3;
    u16* dst = Wb + (size_t)y*1048576;
    const int g = (cv&255)*256 + threadIdx.x;
#pragma unroll
    for (int t=0;t<4;t++){
      const int i4 = g + t*65536;
      const f32x4 v = *(const f32x4*)(src + (size_t)i4*4);
      u16x4 o;
#pragma unroll
      for (int j=0;j<4;j++) o[j] = f2b(v[j]);
      *(u16x4*)(dst + (size_t)i4*4) = o;
    }
    return;
  }
  // A conversion: 4 mats x 16 rows x 128 chunks of 8 u16
  for (int w = threadIdx.x; w < 8192; w += 256){
    const int proj = w >> 11, rem = w & 2047;
    const int row = rem >> 7, c8 = (rem & 127) << 3;
    u16x4 o0 = u16x4{0,0,0,0}, o1 = u16x4{0,0,0,0};
    if (row < 8){
      const float* ap = ((proj==0)?A0:(proj==1)?A1:(proj==2)?A2:A3) + row*1024 + c8;
      const f32x4 v0 = *(const f32x4*)(ap);
      const f32x4 v1 = *(const f32x4*)(ap+4);
#pragma unroll
      for (int j=0;j<4;j++){ o0[j] = f2b(v0[j]); o1[j] = f2b(v1[j]); }
    }
    u16* dp = Abf + (size_t)(proj*16 + row)*1024 + c8;
    *(u16x4*)(dp)   = o0;
    *(u16x4*)(dp+4) = o1;
  }
}

// ---------------- fused QKV GEMM, BK=64; on-the-fly LoRA T; LDS V-transpose --
// grid (24,32): proj = bx>>3 (0=Q,1=K,2=V), n0=(bx&7)*128, m0=by*128.
__global__ __launch_bounds__(256,2) void gemm_qkv_kernel(
    const u16* __restrict__ Xb, const u16* __restrict__ Wb,
    const float* __restrict__ bq, const float* __restrict__ bk, const float* __restrict__ bv,
    const u16* __restrict__ Abf,
    const float* __restrict__ Blq, const float* __restrict__ Blk, const float* __restrict__ Blv,
    u16* __restrict__ Qb, u16* __restrict__ Kb, u16* __restrict__ Vtb)
{
  __shared__ u16 sm[16896];                 // staging (16384) U V-transpose / tT
  u16* AtB = sm;                            // [2][128*32]
  u16* BtB = sm + 8192;                     // [2][128*32]
  const int tid = threadIdx.x;
  const int wid = tid>>6, lane = tid&63;
  const int quad = lane>>4, l16 = lane&15;
  const int wm = wid>>1, wn = wid&1;
  const int proj = blockIdx.x>>3;
  const int n0 = (blockIdx.x&7)<<7, m0 = blockIdx.y<<7;
  const u16* W = Wb + (size_t)proj*1048576;
  const u16* AbP = Abf + (size_t)proj*16384;
  const float* bias = (proj==0)?bq:(proj==1)?bk:bv;
  const float* Bl   = (proj==0)?Blq:(proj==1)?Blk:Blv;
  const float scale = (proj==0)?QSCALE:1.0f;

  f32x4 acc[4][4];
  f32x4 acc_t[4];
#pragma unroll
  for (int i=0;i<4;i++){
#pragma unroll
    for (int j=0;j<4;j++) acc[i][j] = f32x4{0.f,0.f,0.f,0.f};
    acc_t[i] = f32x4{0.f,0.f,0.f,0.f};
  }

  for (int k0=0;k0<1024;k0+=64){
#pragma unroll
    for (int half=0; half<2; half++){
#pragma unroll
      for (int p=0;p<2;p++){
        const int s = wid*128 + p*64 + lane;
        const int row = s>>2, c = s&3;
        load_lds_16B(Xb + (size_t)(m0+row)*1024 + k0 + half*32 + c*8, AtB + half*4096 + (wid*128+p*64)*8);
        load_lds_16B(W  + (size_t)(n0+row)*1024 + k0 + half*32 + c*8, BtB + half*4096 + (wid*128+p*64)*8);
      }
    }
    __syncthreads();
#pragma unroll
    for (int half=0; half<2; half++){
      s16x8 af[4], bfr[4];
#pragma unroll
      for (int t=0;t<4;t++){
        const int r = wm*64 + t*16 + l16;
        af[t]  = *(const s16x8*)(AtB + half*4096 + r*32 + quad*8);
        const int c = wn*64 + t*16 + l16;
        bfr[t] = *(const s16x8*)(BtB + half*4096 + c*32 + quad*8);
      }
      const s16x8 abf = *(const s16x8*)(AbP + (size_t)l16*1024 + k0 + half*32 + quad*8);
#pragma unroll
      for (int tm=0;tm<4;tm++){
#pragma unroll
        for (int tn=0;tn<4;tn++)
          acc[tm][tn] = MFMA16(af[tm], bfr[tn], acc[tm][tn]);
        acc_t[tm] = MFMA16(af[tm], abf, acc_t[tm]);
      }
    }
    __syncthreads();
  }

  // transpose acc_t (C-layout: m=quad*4+rg, r=l16) -> tT[m][r] in LDS
  float* tT = (float*)sm;
  if (wn==0 && l16<8){
#pragma unroll
    for (int tm=0;tm<4;tm++)
#pragma unroll
      for (int rg=0;rg<4;rg++)
        tT[(wm*64 + tm*16 + quad*4 + rg)*8 + l16] = acc_t[tm][rg];
  }
  __syncthreads();

  // LoRA term via one K=8 (zero-padded to 32) MFMA per acc tile: quad0 holds k=0..7
  s16x8 tf[4], bfl[4];
#pragma unroll
  for (int t=0;t<4;t++){ tf[t] = s16x8{0,0,0,0,0,0,0,0}; bfl[t] = s16x8{0,0,0,0,0,0,0,0}; }
  if (quad==0){
#pragma unroll
    for (int tm=0;tm<4;tm++){
      const float* tp = tT + (wm*64 + tm*16 + l16)*8;
#pragma unroll
      for (int j=0;j<8;j++) tf[tm][j] = (short)f2b(2.0f*tp[j]);
    }
#pragma unroll
    for (int tn=0;tn<4;tn++){
      const float* bp = Bl + (size_t)(n0 + wn*64 + tn*16 + l16)*8;
      const f32x4 b0 = *(const f32x4*)(bp);
      const f32x4 b1 = *(const f32x4*)(bp+4);
#pragma unroll
      for (int j=0;j<4;j++){ bfl[tn][j] = (short)f2b(b0[j]); bfl[tn][4+j] = (short)f2b(b1[j]); }
    }
  }
#pragma unroll
  for (int tm=0;tm<4;tm++)
#pragma unroll
    for (int tn=0;tn<4;tn++)
      acc[tm][tn] = MFMA16(tf[tm], bfl[tn], acc[tm][tn]);

  if (proj==2){
    // V: bf16 -> LDS [n_local][m_local] pitch 132 -> coalesced Vt stores
    __syncthreads();   // tT reads done everywhere before sm reuse
#pragma unroll
    for (int tn=0;tn<4;tn++){
      const int nl = wn*64 + tn*16 + l16;
      const float bn = bias[n0+nl];
#pragma unroll
      for (int tm=0;tm<4;tm++){
        const int ml = wm*64 + tm*16 + quad*4;
        u16x4 pk;
#pragma unroll
        for (int rg=0;rg<4;rg++) pk[rg] = f2b(acc[tm][tn][rg]+bn);
        *(u16x4*)(sm + nl*132 + ml) = pk;
      }
    }
    __syncthreads();
    const int batch = m0>>11, sbase = m0&2047;
#pragma unroll
    for (int p=0;p<8;p++){
      const int idx = p*256 + tid;
      const int row = idx>>4, c16 = idx&15;
      const s16x8 v = *(const s16x8*)(sm + row*132 + c16*8);
      const int ng = n0 + row, hh = ng>>6, dd = ng&63;
      *(s16x8*)(Vtb + (size_t)((batch*16+hh)*64+dd)*2048 + sbase + c16*8) = v;
    }
  } else {
#pragma unroll
    for (int tn=0;tn<4;tn++){
      const int n = n0 + wn*64 + tn*16 + l16;
      const float bn = bias[n];
#pragma unroll
      for (int tm=0;tm<4;tm++){
        const int mb = m0 + wm*64 + tm*16 + quad*4;
        if (proj==0){
#pragma unroll
          for (int rg=0;rg<4;rg++) Qb[(size_t)(mb+rg)*1024 + n] = f2b((acc[tm][tn][rg]+bn)*scale);
        } else {
#pragma unroll
          for (int rg=0;rg<4;rg++) Kb[(size_t)(mb+rg)*1024 + n] = f2b(acc[tm][tn][rg]+bn);
        }
      }
    }
  }
}

// ---------------- O-proj GEMM: 128x64, BK=64, on-the-fly LoRA T --------------
__global__ __launch_bounds__(256,2) void gemm_o_kernel(
    const u16* __restrict__ Xb, const u16* __restrict__ W,
    const float* __restrict__ bias, const u16* __restrict__ Abf,
    const float* __restrict__ Bl, float* __restrict__ Out)
{
  __shared__ u16 At[2][128*32];
  __shared__ u16 Bt[2][64*32];
  const int tid = threadIdx.x;
  const int wid = tid>>6, lane = tid&63;
  const int quad = lane>>4, l16 = lane&15;
  const int wm = wid>>1, wn = wid&1;
  const int m0 = blockIdx.y<<7, n0 = blockIdx.x<<6;
  const u16* AbP = Abf + (size_t)3*16384;

  f32x4 acc[4][2];
  f32x4 acc_t[4];
#pragma unroll
  for (int i=0;i<4;i++){
#pragma unroll
    for (int j=0;j<2;j++) acc[i][j] = f32x4{0.f,0.f,0.f,0.f};
    acc_t[i] = f32x4{0.f,0.f,0.f,0.f};
  }

  for (int k0=0;k0<1024;k0+=64){
#pragma unroll
    for (int half=0; half<2; half++){
#pragma unroll
      for (int p=0;p<2;p++){
        const int s = wid*128 + p*64 + lane;
        const int row = s>>2, c = s&3;
        load_lds_16B(Xb + (size_t)(m0+row)*1024 + k0 + half*32 + c*8, At[half] + (wid*128+p*64)*8);
      }
      { const int s = wid*64 + lane;
        const int row = s>>2, c = s&3;
        load_lds_16B(W + (size_t)(n0+row)*1024 + k0 + half*32 + c*8, Bt[half] + (wid*64)*8); }
    }
    __syncthreads();
#pragma unroll
    for (int half=0; half<2; half++){
      s16x8 af[4], bfr[2];
#pragma unroll
      for (int t=0;t<4;t++){
        const int r = wm*64 + t*16 + l16;
        af[t] = *(const s16x8*)(At[half] + r*32 + quad*8);
      }
#pragma unroll
      for (int t=0;t<2;t++){
        const int c = wn*32 + t*16 + l16;
        bfr[t] = *(const s16x8*)(Bt[half] + c*32 + quad*8);
      }
      const s16x8 abf = *(const s16x8*)(AbP + (size_t)l16*1024 + k0 + half*32 + quad*8);
#pragma unroll
      for (int tm=0;tm<4;tm++){
#pragma unroll
        for (int tn=0;tn<2;tn++)
          acc[tm][tn] = MFMA16(af[tm], bfr[tn], acc[tm][tn]);
        acc_t[tm] = MFMA16(af[tm], abf, acc_t[tm]);
      }
    }
    __syncthreads();
  }

  float* tT = (float*)At;
  if (wn==0 && l16<8){
#pragma unroll
    for (int tm=0;tm<4;tm++)
#pragma unroll
      for (int rg=0;rg<4;rg++)
        tT[(wm*64 + tm*16 + quad*4 + rg)*8 + l16] = acc_t[tm][rg];
  }
  __syncthreads();

  s16x8 tf[4], bfl[2];
#pragma unroll
  for (int t=0;t<4;t++) tf[t] = s16x8{0,0,0,0,0,0,0,0};
#pragma unroll
  for (int t=0;t<2;t++) bfl[t] = s16x8{0,0,0,0,0,0,0,0};
  if (quad==0){
#pragma unroll
    for (int tm=0;tm<4;tm++){
      const float* tp = tT + (wm*64 + tm*16 + l16)*8;
#pragma unroll
      for (int j=0;j<8;j++) tf[tm][j] = (short)f2b(2.0f*tp[j]);
    }
#pragma unroll
    for (int tn=0;tn<2;tn++){
      const float* bp = Bl + (size_t)(n0 + wn*32 + tn*16 + l16)*8;
      const f32x4 b0 = *(const f32x4*)(bp);
      const f32x4 b1 = *(const f32x4*)(bp+4);
#pragma unroll
      for (int j=0;j<4;j++){ bfl[tn][j] = (short)f2b(b0[j]); bfl[tn][4+j] = (short)f2b(b1[j]); }
    }
  }
#pragma unroll
  for (int tm=0;tm<4;tm++)
#pragma unroll
    for (int tn=0;tn<2;tn++)
      acc[tm][tn] = MFMA16(tf[tm], bfl[tn], acc[tm][tn]);

#pragma unroll
  for (int tn=0;tn<2;tn++){
    const int n = n0 + wn*32 + tn*16 + l16;
    const float bn = bias[n];
#pragma unroll
    for (int tm=0;tm<4;tm++){
      const int mb = m0 + wm*64 + tm*16 + quad*4;
#pragma unroll
      for (int rg=0;rg<4;rg++)
        Out[(size_t)(mb+rg)*1024 + n] = acc[tm][tn][rg] + bn;
    }
  }
}

// ---------------- MFMA flash attention v8 (verified 47.4-48.2us) -------------
// R15 lesson: the LDS staging below is NOT overhead — the kreg/vreg register
// prefetch (tile t+2 issued under tile t's math) is the latency-hiding engine.
// v9 (direct-global MFMA operands) collapsed to 125us: L2 latency per fragment
// with no prefetch distance. Keep v8.
__global__ __launch_bounds__(512,4) void attn_kernel(
    const u16* __restrict__ Q, const u16* __restrict__ K,
    const u16* __restrict__ Vt, u16* __restrict__ Out)
{
  __shared__ u16 KtB[2][128*72];
  __shared__ u16 VtB[2][64*136];
  const int tid = threadIdx.x;
  const int wid = tid>>6, lane = tid&63;
  const int quad = lane>>4, l16 = lane&15;
  const int lin = blockIdx.x + (blockIdx.y<<4) + (blockIdx.z<<8);
  const int swz = (lin&7)*64 + (lin>>3);
  const int q0 = (swz&15)<<7;
  const int h  = (swz>>4)&15;
  const int nb = swz>>8;
  const int qg = wid>>1;
  const int kh = wid&1;
  const int qw = qg*32;

  s16x8 qf[2][2];
#pragma unroll
  for (int g=0;g<2;g++){
    const int row = q0 + qw + g*16 + l16;
#pragma unroll
    for (int dh=0;dh<2;dh++)
      qf[g][dh] = *(const s16x8*)(Q + (size_t)(nb*2048+row)*1024 + h*64 + dh*32 + quad*8);
  }
  f32x4 OT[2][4];
  f32x4 Lacc[2];
#pragma unroll
  for (int g=0;g<2;g++){
#pragma unroll
    for (int td=0;td<4;td++) OT[g][td] = f32x4{0.f,0.f,0.f,0.f};
    Lacc[g] = f32x4{0.f,0.f,0.f,0.f};
  }
  s16x8 ones;
#pragma unroll
  for (int j=0;j<8;j++) ones[j] = (short)0x3F80;

  s16x8 kreg[2], vreg[2];
  auto LOADT = [&](int kn){
#pragma unroll
    for (int p=0;p<2;p++){
      const int s = p*512 + tid;
      kreg[p] = *(const s16x8*)(K + (size_t)(nb*2048+kn+(s>>3))*1024 + h*64 + (s&7)*8);
      vreg[p] = *(const s16x8*)(Vt + (size_t)((nb*16+h)*64+(s>>4))*2048 + kn + (s&15)*8);
    }
  };
  auto WRITET = [&](int b){
    u16* Ktb = KtB[b]; u16* Vtb = VtB[b];
#pragma unroll
    for (int p=0;p<2;p++){
      const int s = p*512 + tid;
      *(s16x8*)(Ktb + (s>>3)*72 + (s&7)*8) = kreg[p];
      *(s16x8*)(Vtb + (s>>4)*136 + (s&15)*8) = vreg[p];
    }
  };

  LOADT(0);
  WRITET(0);
  LOADT(128);
  __syncthreads();

  for (int t=0;t<16;t++){
    const int cur = t&1;
    if (t < 15) WRITET(cur^1);
    if (t < 14) LOADT((t+2)*128);
    const u16* KtC = KtB[cur];
    const u16* VtC = VtB[cur];

#pragma unroll
    for (int kb=0;kb<2;kb++){
      u32 ew[2][2], ow[2][2];
#pragma unroll
      for (int sel=0;sel<2;sel++){
        const int key = kh*64 + kb*32 + sel*16 + l16;
        const s16x8 kf0 = *(const s16x8*)(KtC + key*72 + quad*8);
        const s16x8 kf1 = *(const s16x8*)(KtC + key*72 + 32 + quad*8);
#pragma unroll
        for (int g=0;g<2;g++){
          f32x4 z = f32x4{0.f,0.f,0.f,0.f};
          z = MFMA16(kf0, qf[g][0], z);
          z = MFMA16(kf1, qf[g][1], z);
          const float p0 = __builtin_amdgcn_exp2f(z[0]);
          const float p1 = __builtin_amdgcn_exp2f(z[1]);
          const float p2 = __builtin_amdgcn_exp2f(z[2]);
          const float p3 = __builtin_amdgcn_exp2f(z[3]);
          const u32 w0 = __builtin_amdgcn_perm(fbits(p1), fbits(p0), 0x07060302u);
          const u32 w1 = __builtin_amdgcn_perm(fbits(p3), fbits(p2), 0x07060302u);
          if (sel==0){ ew[g][0]=w0; ew[g][1]=w1; } else { ow[g][0]=w0; ow[g][1]=w1; }
        }
      }
      s16x8 pf[2];
#pragma unroll
      for (int g=0;g<2;g++){
        const u32x2 r32 = __builtin_amdgcn_permlane32_swap(ew[g][0], ow[g][0], false, false);
        const u32x2 r16 = __builtin_amdgcn_permlane16_swap(r32[0], r32[1], false, false);
        const u32x2 s32 = __builtin_amdgcn_permlane32_swap(ew[g][1], ow[g][1], false, false);
        const u32x2 s16v = __builtin_amdgcn_permlane16_swap(s32[0], s32[1], false, false);
        u32x4 pw; pw[0]=r16[0]; pw[1]=s16v[0]; pw[2]=r16[1]; pw[3]=s16v[1];
        pf[g] = __builtin_bit_cast(s16x8, pw);
      }
      __builtin_amdgcn_s_setprio(1);
#pragma unroll
      for (int td=0;td<4;td++){
        const s16x8 vf = *(const s16x8*)(VtC + (td*16+l16)*136 + kh*64 + kb*32 + quad*8);
#pragma unroll
        for (int g=0;g<2;g++)
          OT[g][td] = MFMA16(vf, pf[g], OT[g][td]);
      }
#pragma unroll
      for (int g=0;g<2;g++)
        Lacc[g] = MFMA16(ones, pf[g], Lacc[g]);
      __builtin_amdgcn_s_setprio(0);
    }
    __syncthreads();
  }

  float* ep = (float*)KtB;
  float* lw = (float*)VtB;
  if (kh==1){
#pragma unroll
    for (int g=0;g<2;g++){
      const int q = qw + g*16 + l16;
#pragma unroll
      for (int td=0;td<4;td++)
        *(f32x4*)(ep + q*68 + td*16 + quad*4) = OT[g][td];
      if (quad==0) lw[q] = Lacc[g][0];
    }
  }
  __syncthreads();
  if (kh==0){
#pragma unroll
    for (int g=0;g<2;g++){
      const int q = qw + g*16 + l16;
      const float linv = 1.0f / (Lacc[g][0] + lw[q]);
      const int qout = q0 + q;
#pragma unroll
      for (int td=0;td<4;td++){
        const f32x4 o2 = *(const f32x4*)(ep + q*68 + td*16 + quad*4);
        u16x4 pk;
#pragma unroll
        for (int rg=0;rg<4;rg++) pk[rg] = f2b((OT[g][td][rg]+o2[rg])*linv);
        *(u16x4*)(Out + (size_t)(nb*2048+qout)*1024 + h*64 + td*16 + quad*4) = pk;
      }
    }
  }
}

extern "C" void kernel_launch(void* const* d_in, const int* in_sizes, int n_in,
                              void* d_out, int out_size, void* d_ws, size_t ws_size,
                              hipStream_t stream)
{
  const float* x  = (const float*)d_in[0];
  const float* Wq = (const float*)d_in[1];  const float* bq = (const float*)d_in[2];
  const float* Aq = (const float*)d_in[3];  const float* Bq = (const float*)d_in[4];
  const float* Wk = (const float*)d_in[5];  const float* bk = (const float*)d_in[6];
  const float* Ak = (const float*)d_in[7];  const float* Bk = (const float*)d_in[8];
  const float* Wv = (const float*)d_in[9];  const float* bv = (const float*)d_in[10];
  const float* Av = (const float*)d_in[11]; const float* Bv = (const float*)d_in[12];
  const float* Wo = (const float*)d_in[13]; const float* bo = (const float*)d_in[14];
  const float* Ao = (const float*)d_in[15]; const float* Bo = (const float*)d_in[16];

  char* ws = (char*)d_ws;
  u16* Abf = (u16*)(ws + 0);                   // 4x16x1024 bf16 = 128 KB
  u16* xb  = (u16*)(ws + 524288);              // 8 MB; Ab aliases (xb dead after QKV)
  u16* Ab  = xb;
  u16* Wb  = (u16*)(ws + 524288 + 8388608);
  u16* Qb  = (u16*)(ws + 524288 + 2*8388608);
  u16* Kb  = (u16*)(ws + 524288 + 3*8388608);
  u16* Vtb = (u16*)(ws + 524288 + 4*8388608);

  conv_kernel<<<dim3(2049),256,0,stream>>>(x, xb, Wq, Wk, Wv, Wo, Wb,
                                           Aq, Ak, Av, Ao, Abf);
  gemm_qkv_kernel<<<dim3(24,32),256,0,stream>>>(xb, Wb, bq, bk, bv, Abf,
                                                Bq, Bk, Bv, Qb, Kb, Vtb);
  attn_kernel<<<dim3(16,16,2),512,0,stream>>>(Qb, Kb, Vtb, Ab);
  gemm_o_kernel<<<dim3(16,32),256,0,stream>>>(Ab, Wb + (size_t)3*1048576, bo, Abf, Bo,
                                              (float*)d_out);
}

// Round 17
// 216.839 us; speedup vs baseline: 1.3760x; 1.0322x over previous
//
#include <hip/hip_runtime.h>
#include <stdint.h>

typedef uint16_t u16;
typedef short s16x8 __attribute__((ext_vector_type(8)));
typedef float f32x4 __attribute__((ext_vector_type(4)));
typedef unsigned short u16x4 __attribute__((ext_vector_type(4)));
typedef uint32_t u32;
typedef u32 u32x2 __attribute__((ext_vector_type(2)));
typedef u32 u32x4 __attribute__((ext_vector_type(4)));

#define MFMA16(a,b,c) __builtin_amdgcn_mfma_f32_16x16x32_bf16((a),(b),(c),0,0,0)
#define QSCALE 0.18033688011112042f   // 0.125 * log2(e)

__device__ __forceinline__ float b2f(u16 b){
  union { u32 u; float f; } v; v.u = ((u32)b)<<16; return v.f;
}
__device__ __forceinline__ u16 f2b(float f){
  union { float f; u32 u; } v; v.f = f;
  return (u16)((v.u + 0x7fffu + ((v.u>>16)&1u))>>16);
}
__device__ __forceinline__ u32 fbits(float f){
  union { float f; u32 u; } v; v.f = f; return v.u;
}
__device__ __forceinline__ void load_lds_16B(const void* g, void* l){
  __builtin_amdgcn_global_load_lds((const __attribute__((address_space(1))) void*)g,
                                   (__attribute__((address_space(3))) void*)l, 16, 0, 0);
}

// ---------------- kernel 1: pure fp32->bf16 conversion (R16-identical) -------
__global__ __launch_bounds__(256) void conv_kernel(
    const float* __restrict__ x, u16* __restrict__ xb,
    const float* __restrict__ W0, const float* __restrict__ W1,
    const float* __restrict__ W2, const float* __restrict__ W3,
    u16* __restrict__ Wb,
    const float* __restrict__ A0, const float* __restrict__ A1,
    const float* __restrict__ A2, const float* __restrict__ A3,
    u16* __restrict__ Abf)
{
  const int bid = blockIdx.x;
  if (bid < 1024){
    const int g = bid*256 + threadIdx.x;
#pragma unroll
    for (int t=0;t<4;t++){
      const int i4 = g + t*262144;
      const f32x4 v = *(const f32x4*)(x + (size_t)i4*4);
      u16x4 o;
#pragma unroll
      for (int j=0;j<4;j++) o[j] = f2b(v[j]);
      *(u16x4*)(xb + (size_t)i4*4) = o;
    }
    return;
  }
  if (bid < 2048){
    const int cv = bid - 1024;
    const int y = cv>>8;
    const float* src = (y==0)?W0:(y==1)?W1:(y==2)?W2:W3;
    u16* dst = Wb + (size_t)y*1048576;
    const int g = (cv&255)*256 + threadIdx.x;
#pragma unroll
    for (int t=0;t<4;t++){
      const int i4 = g + t*65536;
      const f32x4 v = *(const f32x4*)(src + (size_t)i4*4);
      u16x4 o;
#pragma unroll
      for (int j=0;j<4;j++) o[j] = f2b(v[j]);
      *(u16x4*)(dst + (size_t)i4*4) = o;
    }
    return;
  }
  // A conversion: 4 mats x 16 rows x 128 chunks of 8 u16
  for (int w = threadIdx.x; w < 8192; w += 256){
    const int proj = w >> 11, rem = w & 2047;
    const int row = rem >> 7, c8 = (rem & 127) << 3;
    u16x4 o0 = u16x4{0,0,0,0}, o1 = u16x4{0,0,0,0};
    if (row < 8){
      const float* ap = ((proj==0)?A0:(proj==1)?A1:(proj==2)?A2:A3) + row*1024 + c8;
      const f32x4 v0 = *(const f32x4*)(ap);
      const f32x4 v1 = *(const f32x4*)(ap+4);
#pragma unroll
      for (int j=0;j<4;j++){ o0[j] = f2b(v0[j]); o1[j] = f2b(v1[j]); }
    }
    u16* dp = Abf + (size_t)(proj*16 + row)*1024 + c8;
    *(u16x4*)(dp)   = o0;
    *(u16x4*)(dp+4) = o1;
  }
}

// ---------------- fused QKV GEMM (R16-identical) -----------------------------
__global__ __launch_bounds__(256,2) void gemm_qkv_kernel(
    const u16* __restrict__ Xb, const u16* __restrict__ Wb,
    const float* __restrict__ bq, const float* __restrict__ bk, const float* __restrict__ bv,
    const u16* __restrict__ Abf,
    const float* __restrict__ Blq, const float* __restrict__ Blk, const float* __restrict__ Blv,
    u16* __restrict__ Qb, u16* __restrict__ Kb, u16* __restrict__ Vtb)
{
  __shared__ u16 sm[16896];                 // staging (16384) U V-transpose / tT
  u16* AtB = sm;                            // [2][128*32]
  u16* BtB = sm + 8192;                     // [2][128*32]
  const int tid = threadIdx.x;
  const int wid = tid>>6, lane = tid&63;
  const int quad = lane>>4, l16 = lane&15;
  const int wm = wid>>1, wn = wid&1;
  const int proj = blockIdx.x>>3;
  const int n0 = (blockIdx.x&7)<<7, m0 = blockIdx.y<<7;
  const u16* W = Wb + (size_t)proj*1048576;
  const u16* AbP = Abf + (size_t)proj*16384;
  const float* bias = (proj==0)?bq:(proj==1)?bk:bv;
  const float* Bl   = (proj==0)?Blq:(proj==1)?Blk:Blv;
  const float scale = (proj==0)?QSCALE:1.0f;

  f32x4 acc[4][4];
  f32x4 acc_t[4];
#pragma unroll
  for (int i=0;i<4;i++){
#pragma unroll
    for (int j=0;j<4;j++) acc[i][j] = f32x4{0.f,0.f,0.f,0.f};
    acc_t[i] = f32x4{0.f,0.f,0.f,0.f};
  }

  for (int k0=0;k0<1024;k0+=64){
#pragma unroll
    for (int half=0; half<2; half++){
#pragma unroll
      for (int p=0;p<2;p++){
        const int s = wid*128 + p*64 + lane;
        const int row = s>>2, c = s&3;
        load_lds_16B(Xb + (size_t)(m0+row)*1024 + k0 + half*32 + c*8, AtB + half*4096 + (wid*128+p*64)*8);
        load_lds_16B(W  + (size_t)(n0+row)*1024 + k0 + half*32 + c*8, BtB + half*4096 + (wid*128+p*64)*8);
      }
    }
    __syncthreads();
#pragma unroll
    for (int half=0; half<2; half++){
      s16x8 af[4], bfr[4];
#pragma unroll
      for (int t=0;t<4;t++){
        const int r = wm*64 + t*16 + l16;
        af[t]  = *(const s16x8*)(AtB + half*4096 + r*32 + quad*8);
        const int c = wn*64 + t*16 + l16;
        bfr[t] = *(const s16x8*)(BtB + half*4096 + c*32 + quad*8);
      }
      const s16x8 abf = *(const s16x8*)(AbP + (size_t)l16*1024 + k0 + half*32 + quad*8);
#pragma unroll
      for (int tm=0;tm<4;tm++){
#pragma unroll
        for (int tn=0;tn<4;tn++)
          acc[tm][tn] = MFMA16(af[tm], bfr[tn], acc[tm][tn]);
        acc_t[tm] = MFMA16(af[tm], abf, acc_t[tm]);
      }
    }
    __syncthreads();
  }

  // transpose acc_t (C-layout: m=quad*4+rg, r=l16) -> tT[m][r] in LDS
  float* tT = (float*)sm;
  if (wn==0 && l16<8){
#pragma unroll
    for (int tm=0;tm<4;tm++)
#pragma unroll
      for (int rg=0;rg<4;rg++)
        tT[(wm*64 + tm*16 + quad*4 + rg)*8 + l16] = acc_t[tm][rg];
  }
  __syncthreads();

  // LoRA term via one K=8 (zero-padded to 32) MFMA per acc tile: quad0 holds k=0..7
  s16x8 tf[4], bfl[4];
#pragma unroll
  for (int t=0;t<4;t++){ tf[t] = s16x8{0,0,0,0,0,0,0,0}; bfl[t] = s16x8{0,0,0,0,0,0,0,0}; }
  if (quad==0){
#pragma unroll
    for (int tm=0;tm<4;tm++){
      const float* tp = tT + (wm*64 + tm*16 + l16)*8;
#pragma unroll
      for (int j=0;j<8;j++) tf[tm][j] = (short)f2b(2.0f*tp[j]);
    }
#pragma unroll
    for (int tn=0;tn<4;tn++){
      const float* bp = Bl + (size_t)(n0 + wn*64 + tn*16 + l16)*8;
      const f32x4 b0 = *(const f32x4*)(bp);
      const f32x4 b1 = *(const f32x4*)(bp+4);
#pragma unroll
      for (int j=0;j<4;j++){ bfl[tn][j] = (short)f2b(b0[j]); bfl[tn][4+j] = (short)f2b(b1[j]); }
    }
  }
#pragma unroll
  for (int tm=0;tm<4;tm++)
#pragma unroll
    for (int tn=0;tn<4;tn++)
      acc[tm][tn] = MFMA16(tf[tm], bfl[tn], acc[tm][tn]);

  if (proj==2){
    // V: bf16 -> LDS [n_local][m_local] pitch 132 -> coalesced Vt stores
    __syncthreads();   // tT reads done everywhere before sm reuse
#pragma unroll
    for (int tn=0;tn<4;tn++){
      const int nl = wn*64 + tn*16 + l16;
      const float bn = bias[n0+nl];
#pragma unroll
      for (int tm=0;tm<4;tm++){
        const int ml = wm*64 + tm*16 + quad*4;
        u16x4 pk;
#pragma unroll
        for (int rg=0;rg<4;rg++) pk[rg] = f2b(acc[tm][tn][rg]+bn);
        *(u16x4*)(sm + nl*132 + ml) = pk;
      }
    }
    __syncthreads();
    const int batch = m0>>11, sbase = m0&2047;
#pragma unroll
    for (int p=0;p<8;p++){
      const int idx = p*256 + tid;
      const int row = idx>>4, c16 = idx&15;
      const s16x8 v = *(const s16x8*)(sm + row*132 + c16*8);
      const int ng = n0 + row, hh = ng>>6, dd = ng&63;
      *(s16x8*)(Vtb + (size_t)((batch*16+hh)*64+dd)*2048 + sbase + c16*8) = v;
    }
  } else {
#pragma unroll
    for (int tn=0;tn<4;tn++){
      const int n = n0 + wn*64 + tn*16 + l16;
      const float bn = bias[n];
#pragma unroll
      for (int tm=0;tm<4;tm++){
        const int mb = m0 + wm*64 + tm*16 + quad*4;
        if (proj==0){
#pragma unroll
          for (int rg=0;rg<4;rg++) Qb[(size_t)(mb+rg)*1024 + n] = f2b((acc[tm][tn][rg]+bn)*scale);
        } else {
#pragma unroll
          for (int rg=0;rg<4;rg++) Kb[(size_t)(mb+rg)*1024 + n] = f2b(acc[tm][tn][rg]+bn);
        }
      }
    }
  }
}

// ---------------- O-proj GEMM v2: in-block split-K, 512 threads --------------
// R16 ledger: gemm_o never in top-5 but est. 35-46us (17.2 GFLOP at this
// structure's rate, 2 blocks/CU = 25% occ ceiling, 32 serial barrier-drains).
// Split-K (R5's proven attn trick, +17%): waves 0-3 own K[0,512), waves 4-7
// own K[512,1024), own LDS buffers, per-wave fragment structure IDENTICAL to
// the verified 4-wave code. Serial K-depth & barriers halve (16->8 steps),
// waves/CU double (8->16). LDS epilogue merges partial acc/acc_t (f32 add,
// ~1e-5 reorder noise). LDS 48KB; grid (16,32)=512=2 blocks/CU.
__global__ __launch_bounds__(512,4) void gemm_o_kernel(
    const u16* __restrict__ Xb, const u16* __restrict__ W,
    const float* __restrict__ bias, const u16* __restrict__ Abf,
    const float* __restrict__ Bl, float* __restrict__ Out)
{
  __shared__ char smem[49152];
  const int tid = threadIdx.x;
  const int wid = tid>>6, lane = tid&63;
  const int quad = lane>>4, l16 = lane&15;
  const int kseg = wid>>2;                   // 0,1: K-segment
  const int w4 = wid&3;                      // wave within segment
  const int wm = w4>>1, wn = w4&1;
  const int m0 = blockIdx.y<<7, n0 = blockIdx.x<<6;
  const u16* AbP = Abf + (size_t)3*16384;
  const int kbase = kseg<<9;

  u16* At = (u16*)smem + kseg*8192;          // per kseg: [2 halves][128*32]
  u16* Bt = (u16*)smem + 16384 + kseg*4096;  // per kseg: [2 halves][64*32]

  f32x4 acc[4][2];
  f32x4 acc_t[4];
#pragma unroll
  for (int i=0;i<4;i++){
#pragma unroll
    for (int j=0;j<2;j++) acc[i][j] = f32x4{0.f,0.f,0.f,0.f};
    acc_t[i] = f32x4{0.f,0.f,0.f,0.f};
  }

  for (int k0=kbase; k0<kbase+512; k0+=64){
#pragma unroll
    for (int half=0; half<2; half++){
#pragma unroll
      for (int p=0;p<2;p++){
        const int s = w4*128 + p*64 + lane;
        const int row = s>>2, c = s&3;
        load_lds_16B(Xb + (size_t)(m0+row)*1024 + k0 + half*32 + c*8, At + half*4096 + (w4*128+p*64)*8);
      }
      { const int s = w4*64 + lane;
        const int row = s>>2, c = s&3;
        load_lds_16B(W + (size_t)(n0+row)*1024 + k0 + half*32 + c*8, Bt + half*2048 + (w4*64)*8); }
    }
    __syncthreads();
#pragma unroll
    for (int half=0; half<2; half++){
      s16x8 af[4], bfr[2];
#pragma unroll
      for (int t=0;t<4;t++){
        const int r = wm*64 + t*16 + l16;
        af[t] = *(const s16x8*)(At + half*4096 + r*32 + quad*8);
      }
#pragma unroll
      for (int t=0;t<2;t++){
        const int c = wn*32 + t*16 + l16;
        bfr[t] = *(const s16x8*)(Bt + half*2048 + c*32 + quad*8);
      }
      const s16x8 abf = *(const s16x8*)(AbP + (size_t)l16*1024 + k0 + half*32 + quad*8);
#pragma unroll
      for (int tm=0;tm<4;tm++){
#pragma unroll
        for (int tn=0;tn<2;tn++)
          acc[tm][tn] = MFMA16(af[tm], bfr[tn], acc[tm][tn]);
        acc_t[tm] = MFMA16(af[tm], abf, acc_t[tm]);
      }
    }
    __syncthreads();
  }

  // ---- merge K-segments via LDS (staging buffers dead after last barrier) ---
  float* ep  = (float*)smem;                 // 128x68 f32 = 34816 B
  float* tTp = (float*)(smem + 35072);       // 128x8 f32 = 4096 B
  if (kseg==1){
#pragma unroll
    for (int tn=0;tn<2;tn++)
#pragma unroll
      for (int tm=0;tm<4;tm++)
#pragma unroll
        for (int rg=0;rg<4;rg++)
          ep[(wm*64+tm*16+quad*4+rg)*68 + wn*32+tn*16+l16] = acc[tm][tn][rg];
    if (wn==0 && l16<8){
#pragma unroll
      for (int tm=0;tm<4;tm++)
#pragma unroll
        for (int rg=0;rg<4;rg++)
          tTp[(wm*64+tm*16+quad*4+rg)*8 + l16] = acc_t[tm][rg];
    }
  }
  __syncthreads();
  if (kseg==0){
#pragma unroll
    for (int tn=0;tn<2;tn++)
#pragma unroll
      for (int tm=0;tm<4;tm++)
#pragma unroll
        for (int rg=0;rg<4;rg++)
          acc[tm][tn][rg] += ep[(wm*64+tm*16+quad*4+rg)*68 + wn*32+tn*16+l16];
    if (wn==0 && l16<8){
#pragma unroll
      for (int tm=0;tm<4;tm++)
#pragma unroll
        for (int rg=0;rg<4;rg++)
          tTp[(wm*64+tm*16+quad*4+rg)*8 + l16] += acc_t[tm][rg];
    }
  }
  __syncthreads();   // tTp merge visible to kseg0's tf-builders

  if (kseg==0){
    // LoRA term via one K=8 (zero-padded to 32) MFMA; tTp already in tT layout
    s16x8 tf[4], bfl[2];
#pragma unroll
    for (int t=0;t<4;t++) tf[t] = s16x8{0,0,0,0,0,0,0,0};
#pragma unroll
    for (int t=0;t<2;t++) bfl[t] = s16x8{0,0,0,0,0,0,0,0};
    if (quad==0){
#pragma unroll
      for (int tm=0;tm<4;tm++){
        const float* tp = tTp + (wm*64 + tm*16 + l16)*8;
#pragma unroll
        for (int j=0;j<8;j++) tf[tm][j] = (short)f2b(2.0f*tp[j]);
      }
#pragma unroll
      for (int tn=0;tn<2;tn++){
        const float* bp = Bl + (size_t)(n0 + wn*32 + tn*16 + l16)*8;
        const f32x4 b0 = *(const f32x4*)(bp);
        const f32x4 b1 = *(const f32x4*)(bp+4);
#pragma unroll
        for (int j=0;j<4;j++){ bfl[tn][j] = (short)f2b(b0[j]); bfl[tn][4+j] = (short)f2b(b1[j]); }
      }
    }
#pragma unroll
    for (int tm=0;tm<4;tm++)
#pragma unroll
      for (int tn=0;tn<2;tn++)
        acc[tm][tn] = MFMA16(tf[tm], bfl[tn], acc[tm][tn]);

#pragma unroll
    for (int tn=0;tn<2;tn++){
      const int n = n0 + wn*32 + tn*16 + l16;
      const float bn = bias[n];
#pragma unroll
      for (int tm=0;tm<4;tm++){
        const int mb = m0 + wm*64 + tm*16 + quad*4;
#pragma unroll
        for (int rg=0;rg<4;rg++)
          Out[(size_t)(mb+rg)*1024 + n] = acc[tm][tn][rg] + bn;
      }
    }
  }
}

// ---------------- MFMA flash attention v8 (R16-identical, verified) ----------
__global__ __launch_bounds__(512,4) void attn_kernel(
    const u16* __restrict__ Q, const u16* __restrict__ K,
    const u16* __restrict__ Vt, u16* __restrict__ Out)
{
  __shared__ u16 KtB[2][128*72];
  __shared__ u16 VtB[2][64*136];
  const int tid = threadIdx.x;
  const int wid = tid>>6, lane = tid&63;
  const int quad = lane>>4, l16 = lane&15;
  const int lin = blockIdx.x + (blockIdx.y<<4) + (blockIdx.z<<8);
  const int swz = (lin&7)*64 + (lin>>3);
  const int q0 = (swz&15)<<7;
  const int h  = (swz>>4)&15;
  const int nb = swz>>8;
  const int qg = wid>>1;
  const int kh = wid&1;
  const int qw = qg*32;

  s16x8 qf[2][2];
#pragma unroll
  for (int g=0;g<2;g++){
    const int row = q0 + qw + g*16 + l16;
#pragma unroll
    for (int dh=0;dh<2;dh++)
      qf[g][dh] = *(const s16x8*)(Q + (size_t)(nb*2048+row)*1024 + h*64 + dh*32 + quad*8);
  }
  f32x4 OT[2][4];
  f32x4 Lacc[2];
#pragma unroll
  for (int g=0;g<2;g++){
#pragma unroll
    for (int td=0;td<4;td++) OT[g][td] = f32x4{0.f,0.f,0.f,0.f};
    Lacc[g] = f32x4{0.f,0.f,0.f,0.f};
  }
  s16x8 ones;
#pragma unroll
  for (int j=0;j<8;j++) ones[j] = (short)0x3F80;

  s16x8 kreg[2], vreg[2];
  auto LOADT = [&](int kn){
#pragma unroll
    for (int p=0;p<2;p++){
      const int s = p*512 + tid;
      kreg[p] = *(const s16x8*)(K + (size_t)(nb*2048+kn+(s>>3))*1024 + h*64 + (s&7)*8);
      vreg[p] = *(const s16x8*)(Vt + (size_t)((nb*16+h)*64+(s>>4))*2048 + kn + (s&15)*8);
    }
  };
  auto WRITET = [&](int b){
    u16* Ktb = KtB[b]; u16* Vtb = VtB[b];
#pragma unroll
    for (int p=0;p<2;p++){
      const int s = p*512 + tid;
      *(s16x8*)(Ktb + (s>>3)*72 + (s&7)*8) = kreg[p];
      *(s16x8*)(Vtb + (s>>4)*136 + (s&15)*8) = vreg[p];
    }
  };

  LOADT(0);
  WRITET(0);
  LOADT(128);
  __syncthreads();

  for (int t=0;t<16;t++){
    const int cur = t&1;
    if (t < 15) WRITET(cur^1);
    if (t < 14) LOADT((t+2)*128);
    const u16* KtC = KtB[cur];
    const u16* VtC = VtB[cur];

#pragma unroll
    for (int kb=0;kb<2;kb++){
      u32 ew[2][2], ow[2][2];
#pragma unroll
      for (int sel=0;sel<2;sel++){
        const int key = kh*64 + kb*32 + sel*16 + l16;
        const s16x8 kf0 = *(const s16x8*)(KtC + key*72 + quad*8);
        const s16x8 kf1 = *(const s16x8*)(KtC + key*72 + 32 + quad*8);
#pragma unroll
        for (int g=0;g<2;g++){
          f32x4 z = f32x4{0.f,0.f,0.f,0.f};
          z = MFMA16(kf0, qf[g][0], z);
          z = MFMA16(kf1, qf[g][1], z);
          const float p0 = __builtin_amdgcn_exp2f(z[0]);
          const float p1 = __builtin_amdgcn_exp2f(z[1]);
          const float p2 = __builtin_amdgcn_exp2f(z[2]);
          const float p3 = __builtin_amdgcn_exp2f(z[3]);
          const u32 w0 = __builtin_amdgcn_perm(fbits(p1), fbits(p0), 0x07060302u);
          const u32 w1 = __builtin_amdgcn_perm(fbits(p3), fbits(p2), 0x07060302u);
          if (sel==0){ ew[g][0]=w0; ew[g][1]=w1; } else { ow[g][0]=w0; ow[g][1]=w1; }
        }
      }
      s16x8 pf[2];
#pragma unroll
      for (int g=0;g<2;g++){
        const u32x2 r32 = __builtin_amdgcn_permlane32_swap(ew[g][0], ow[g][0], false, false);
        const u32x2 r16 = __builtin_amdgcn_permlane16_swap(r32[0], r32[1], false, false);
        const u32x2 s32 = __builtin_amdgcn_permlane32_swap(ew[g][1], ow[g][1], false, false);
        const u32x2 s16v = __builtin_amdgcn_permlane16_swap(s32[0], s32[1], false, false);
        u32x4 pw; pw[0]=r16[0]; pw[1]=s16v[0]; pw[2]=r16[1]; pw[3]=s16v[1];
        pf[g] = __builtin_bit_cast(s16x8, pw);
      }
      __builtin_amdgcn_s_setprio(1);
#pragma unroll
      for (int td=0;td<4;td++){
        const s16x8 vf = *(const s16x8*)(VtC + (td*16+l16)*136 + kh*64 + kb*32 + quad*8);
#pragma unroll
        for (int g=0;g<2;g++)
          OT[g][td] = MFMA16(vf, pf[g], OT[g][td]);
      }
#pragma unroll
      for (int g=0;g<2;g++)
        Lacc[g] = MFMA16(ones, pf[g], Lacc[g]);
      __builtin_amdgcn_s_setprio(0);
    }
    __syncthreads();
  }

  float* ep = (float*)KtB;
  float* lw = (float*)VtB;
  if (kh==1){
#pragma unroll
    for (int g=0;g<2;g++){
      const int q = qw + g*16 + l16;
#pragma unroll
      for (int td=0;td<4;td++)
        *(f32x4*)(ep + q*68 + td*16 + quad*4) = OT[g][td];
      if (quad==0) lw[q] = Lacc[g][0];
    }
  }
  __syncthreads();
  if (kh==0){
#pragma unroll
    for (int g=0;g<2;g++){
      const int q = qw + g*16 + l16;
      const float linv = 1.0f / (Lacc[g][0] + lw[q]);
      const int qout = q0 + q;
#pragma unroll
      for (int td=0;td<4;td++){
        const f32x4 o2 = *(const f32x4*)(ep + q*68 + td*16 + quad*4);
        u16x4 pk;
#pragma unroll
        for (int rg=0;rg<4;rg++) pk[rg] = f2b((OT[g][td][rg]+o2[rg])*linv);
        *(u16x4*)(Out + (size_t)(nb*2048+qout)*1024 + h*64 + td*16 + quad*4) = pk;
      }
    }
  }
}

extern "C" void kernel_launch(void* const* d_in, const int* in_sizes, int n_in,
                              void* d_out, int out_size, void* d_ws, size_t ws_size,
                              hipStream_t stream)
{
  const float* x  = (const float*)d_in[0];
  const float* Wq = (const float*)d_in[1];  const float* bq = (const float*)d_in[2];
  const float* Aq = (const float*)d_in[3];  const float* Bq = (const float*)d_in[4];
  const float* Wk = (const float*)d_in[5];  const float* bk = (const float*)d_in[6];
  const float* Ak = (const float*)d_in[7];  const float* Bk = (const float*)d_in[8];
  const float* Wv = (const float*)d_in[9];  const float* bv = (const float*)d_in[10];
  const float* Av = (const float*)d_in[11]; const float* Bv = (const float*)d_in[12];
  const float* Wo = (const float*)d_in[13]; const float* bo = (const float*)d_in[14];
  const float* Ao = (const float*)d_in[15]; const float* Bo = (const float*)d_in[16];

  char* ws = (char*)d_ws;
  u16* Abf = (u16*)(ws + 0);                   // 4x16x1024 bf16 = 128 KB
  u16* xb  = (u16*)(ws + 524288);              // 8 MB; Ab aliases (xb dead after QKV)
  u16* Ab  = xb;
  u16* Wb  = (u16*)(ws + 524288 + 8388608);
  u16* Qb  = (u16*)(ws + 524288 + 2*8388608);
  u16* Kb  = (u16*)(ws + 524288 + 3*8388608);
  u16* Vtb = (u16*)(ws + 524288 + 4*8388608);

  conv_kernel<<<dim3(2049),256,0,stream>>>(x, xb, Wq, Wk, Wv, Wo, Wb,
                                           Aq, Ak, Av, Ao, Abf);
  gemm_qkv_kernel<<<dim3(24,32),256,0,stream>>>(xb, Wb, bq, bk, bv, Abf,
                                                Bq, Bk, Bv, Qb, Kb, Vtb);
  attn_kernel<<<dim3(16,16,2),512,0,stream>>>(Qb, Kb, Vtb, Ab);
  gemm_o_kernel<<<dim3(16,32),512,0,stream>>>(Ab, Wb + (size_t)3*1048576, bo, Abf, Bo,
                                              (float*)d_out);
}